// Round 1
// baseline (2247.445 us; speedup 1.0000x reference)
//
#include <hip/hip_runtime.h>
#include <hip/hip_bf16.h>

// Problem: bidirectional GRU (Keras reset_after=True) + dense classifier.
// B=32, T=160, D=512, H=256, C=6625.
// Round 1: pure-fp32 correctness baseline.
//   K1 proj: xp[dir][s][b][0:768] = x_t(row) @ kernel_dir + bias_dir[0]
//   K2 scan: 64 blocks = (dir,batch), h kept in LDS, rk streamed from L2.
//   K3 cls : hcat[t][b][0:512] @ W + b -> logits [T][B][C]

#define B 32
#define T 160
#define D 512
#define H 256
#define C 6625
#define H3 768

// ---------------------------------------------------------------- K1: proj
// grid (3, 160, 2), block 256. Block computes 32 rows (b=0..31, fixed s) x 256 cols.
__global__ __launch_bounds__(256) void proj_kernel(
    const float* __restrict__ x,       // [B][T][D]
    const float* __restrict__ kf,      // [D][H3]
    const float* __restrict__ kb,
    const float* __restrict__ bias_f,  // [2][H3]
    const float* __restrict__ bias_b,
    float* __restrict__ xp)            // [2][T][B][H3]
{
    const int ct  = blockIdx.x;        // col tile 0..2
    const int s   = blockIdx.y;        // scan index 0..159
    const int dir = blockIdx.z;
    const int tid = threadIdx.x;
    const int t   = dir ? (T - 1 - s) : s;     // actual time of this scan row
    const float* kern = dir ? kb : kf;
    const float* bias = dir ? bias_b : bias_f;

    __shared__ float xs[32 * 512];     // 64 KB: x rows for b=0..31 at time t
    for (int it = 0; it < 16; ++it) {
        int v   = it * 256 + tid;      // float4 slot 0..4095
        int row = v >> 7;              // b
        int k4  = v & 127;
        *(float4*)&xs[(row << 9) + (k4 << 2)] =
            *(const float4*)&x[((row * T + t) << 9) + (k4 << 2)];
    }
    __syncthreads();

    const int col = ct * 256 + tid;    // 0..767
    float acc[32];
#pragma unroll
    for (int r = 0; r < 32; ++r) acc[r] = 0.f;

    for (int k = 0; k < 512; k += 4) {
        float w0 = kern[(k + 0) * H3 + col];
        float w1 = kern[(k + 1) * H3 + col];
        float w2 = kern[(k + 2) * H3 + col];
        float w3 = kern[(k + 3) * H3 + col];
#pragma unroll
        for (int r = 0; r < 32; ++r) {
            float4 xv = *(const float4*)&xs[(r << 9) + k];  // broadcast read
            acc[r] += xv.x * w0 + xv.y * w1 + xv.z * w2 + xv.w * w3;
        }
    }

    const float bb = bias[col];        // bias[0][col]
    for (int r = 0; r < 32; ++r)
        xp[((dir * T + s) * B + r) * H3 + col] = acc[r] + bb;
}

// ---------------------------------------------------------------- K2: scan
// grid 64 = (dir<<5)|b, block 256 (thread j = hidden index).
__global__ __launch_bounds__(256) void gru_scan_kernel(
    const float* __restrict__ xp,      // [2][T][B][H3]
    const float* __restrict__ rk_f,    // [H][H3]
    const float* __restrict__ rk_b,
    const float* __restrict__ bias_f,  // [2][H3]
    const float* __restrict__ bias_b,
    float* __restrict__ hcat)          // [T][B][2H]
{
    const int bid = blockIdx.x;
    const int dir = bid >> 5;
    const int b   = bid & 31;
    const int j   = threadIdx.x;       // 0..255
    const float* rk   = dir ? rk_b : rk_f;
    const float* bias = dir ? bias_b : bias_f;
    const float rbz = bias[H3 + j];
    const float rbr = bias[H3 + 256 + j];
    const float rbh = bias[H3 + 512 + j];

    __shared__ float h[256];
    h[j] = 0.f;
    __syncthreads();

    for (int s = 0; s < T; ++s) {
        const float* xrow = xp + ((dir * T + s) * B + b) * H3;
        float az = 0.f, ar = 0.f, ah = 0.f;
        for (int k = 0; k < 256; k += 4) {
            float4 h4 = *(const float4*)&h[k];              // LDS broadcast
            const float* rkp = rk + k * H3 + j;
            az += h4.x * rkp[0];
            ar += h4.x * rkp[256];
            ah += h4.x * rkp[512];
            az += h4.y * rkp[H3];
            ar += h4.y * rkp[H3 + 256];
            ah += h4.y * rkp[H3 + 512];
            az += h4.z * rkp[2 * H3];
            ar += h4.z * rkp[2 * H3 + 256];
            ah += h4.z * rkp[2 * H3 + 512];
            az += h4.w * rkp[3 * H3];
            ar += h4.w * rkp[3 * H3 + 256];
            ah += h4.w * rkp[3 * H3 + 512];
        }
        const float xz = xrow[j], xr = xrow[256 + j], xh = xrow[512 + j];
        const float z  = 1.f / (1.f + __expf(-(xz + az + rbz)));
        const float r  = 1.f / (1.f + __expf(-(xr + ar + rbr)));
        const float pre = xh + r * (ah + rbh);
        const float e2  = __expf(2.f * pre);
        const float hh  = 1.f - 2.f / (e2 + 1.f);           // tanh, inf-safe
        const float hn  = z * h[j] + (1.f - z) * hh;
        __syncthreads();
        h[j] = hn;
        __syncthreads();
        const int ta = dir ? (T - 1 - s) : s;               // actual time
        hcat[(ta * B + b) * (2 * H) + dir * H + j] = hn;
    }
}

// ---------------------------------------------------------------- K3: classifier
// grid (13, 160), block 256. Block = 32 rows x 512 cols; thread = 2 cols x 32 rows.
__global__ __launch_bounds__(256) void cls_kernel(
    const float* __restrict__ hcat,    // [5120][512]
    const float* __restrict__ W,       // [512][C]
    const float* __restrict__ bias,    // [C]
    float* __restrict__ out)           // [5120][C]
{
    const int ct  = blockIdx.x;        // 0..12
    const int rt  = blockIdx.y;        // 0..159
    const int tid = threadIdx.x;
    const int r0  = rt * 32;

    __shared__ float hs[32 * 512];     // 64 KB
    for (int it = 0; it < 16; ++it) {
        int v   = it * 256 + tid;
        int row = v >> 7;
        int k4  = v & 127;
        *(float4*)&hs[(row << 9) + (k4 << 2)] =
            *(const float4*)&hcat[((r0 + row) << 9) + (k4 << 2)];
    }
    __syncthreads();

    const int c0 = ct * 512 + tid;     // always < 6625 (max 6399)
    const int c1 = c0 + 256;
    const bool v1 = (c1 < C);

    float acc0[32], acc1[32];
#pragma unroll
    for (int r = 0; r < 32; ++r) { acc0[r] = 0.f; acc1[r] = 0.f; }

    for (int k = 0; k < 512; k += 4) {
        const float* wp = W + k * C;
        float w00 = wp[c0];
        float w01 = wp[C + c0];
        float w02 = wp[2 * C + c0];
        float w03 = wp[3 * C + c0];
        float w10 = v1 ? wp[c1] : 0.f;
        float w11 = v1 ? wp[C + c1] : 0.f;
        float w12 = v1 ? wp[2 * C + c1] : 0.f;
        float w13 = v1 ? wp[3 * C + c1] : 0.f;
#pragma unroll
        for (int r = 0; r < 32; ++r) {
            float4 hv = *(const float4*)&hs[(r << 9) + k];  // broadcast read
            acc0[r] += hv.x * w00 + hv.y * w01 + hv.z * w02 + hv.w * w03;
            acc1[r] += hv.x * w10 + hv.y * w11 + hv.z * w12 + hv.w * w13;
        }
    }

    const float b0 = bias[c0];
    const float b1 = v1 ? bias[c1] : 0.f;
    for (int r = 0; r < 32; ++r) {
        out[(size_t)(r0 + r) * C + c0] = acc0[r] + b0;
        if (v1) out[(size_t)(r0 + r) * C + c1] = acc1[r] + b1;
    }
}

// ---------------------------------------------------------------- launch
extern "C" void kernel_launch(void* const* d_in, const int* in_sizes, int n_in,
                              void* d_out, int out_size, void* d_ws, size_t ws_size,
                              hipStream_t stream) {
    const float* x       = (const float*)d_in[0];
    const float* kf      = (const float*)d_in[1];
    const float* rkf     = (const float*)d_in[2];
    const float* biasf   = (const float*)d_in[3];
    const float* kb      = (const float*)d_in[4];
    const float* rkb     = (const float*)d_in[5];
    const float* biasb   = (const float*)d_in[6];
    const float* W       = (const float*)d_in[7];
    const float* bvec    = (const float*)d_in[8];
    float* out = (float*)d_out;

    const size_t xp_elems   = (size_t)2 * T * B * H3;   // 7,864,320
    const size_t hcat_elems = (size_t)T * B * 2 * H;    // 2,621,440

    float* xp;
    float* hcat;
    if (ws_size >= (xp_elems + hcat_elems) * sizeof(float)) {
        xp   = (float*)d_ws;
        hcat = xp + xp_elems;
    } else {
        // xp is dead before K3 writes out: reuse d_out as xp scratch.
        xp   = out;                 // 7.86M floats <= out_size 33.92M
        hcat = (float*)d_ws;        // needs 10.5 MB
    }

    dim3 g1(3, T, 2);
    proj_kernel<<<g1, 256, 0, stream>>>(x, kf, kb, biasf, biasb, xp);

    gru_scan_kernel<<<64, 256, 0, stream>>>(xp, rkf, rkb, biasf, biasb, hcat);

    dim3 g3(13, T);
    cls_kernel<<<g3, 256, 0, stream>>>(hcat, W, bvec, out);
}

// Round 2
// 1989.148 us; speedup vs baseline: 1.1299x; 1.1299x over previous
//
#include <hip/hip_runtime.h>
#include <hip/hip_bf16.h>

// Bidirectional GRU (Keras reset_after=True) + dense classifier.
// B=32, T=160, D=512, H=256, C=6625.
// Round 2: scan restructure for latency hiding (1024 thr, 4-way k-split),
//          cls block remap for W L2-residency. All fp32 still.

#define B 32
#define T 160
#define D 512
#define H 256
#define C 6625
#define H3 768

// ---------------------------------------------------------------- K1: proj
// grid (3, 160, 2), block 256. Block computes 32 rows (b=0..31, fixed s) x 256 cols.
__global__ __launch_bounds__(256) void proj_kernel(
    const float* __restrict__ x,       // [B][T][D]
    const float* __restrict__ kf,      // [D][H3]
    const float* __restrict__ kb,
    const float* __restrict__ bias_f,  // [2][H3]
    const float* __restrict__ bias_b,
    float* __restrict__ xp)            // [2][T][B][H3]
{
    const int ct  = blockIdx.x;        // col tile 0..2
    const int s   = blockIdx.y;        // scan index 0..159
    const int dir = blockIdx.z;
    const int tid = threadIdx.x;
    const int t   = dir ? (T - 1 - s) : s;     // actual time of this scan row
    const float* kern = dir ? kb : kf;
    const float* bias = dir ? bias_b : bias_f;

    __shared__ float xs[32 * 512];     // 64 KB: x rows for b=0..31 at time t
    for (int it = 0; it < 16; ++it) {
        int v   = it * 256 + tid;      // float4 slot 0..4095
        int row = v >> 7;              // b
        int k4  = v & 127;
        *(float4*)&xs[(row << 9) + (k4 << 2)] =
            *(const float4*)&x[((row * T + t) << 9) + (k4 << 2)];
    }
    __syncthreads();

    const int col = ct * 256 + tid;    // 0..767
    float acc[32];
#pragma unroll
    for (int r = 0; r < 32; ++r) acc[r] = 0.f;

    for (int k = 0; k < 512; k += 4) {
        float w0 = kern[(k + 0) * H3 + col];
        float w1 = kern[(k + 1) * H3 + col];
        float w2 = kern[(k + 2) * H3 + col];
        float w3 = kern[(k + 3) * H3 + col];
#pragma unroll
        for (int r = 0; r < 32; ++r) {
            float4 xv = *(const float4*)&xs[(r << 9) + k];  // broadcast read
            acc[r] += xv.x * w0 + xv.y * w1 + xv.z * w2 + xv.w * w3;
        }
    }

    const float bb = bias[col];        // bias[0][col]
    for (int r = 0; r < 32; ++r)
        xp[((dir * T + s) * B + r) * H3 + col] = acc[r] + bb;
}

// ---------------------------------------------------------------- K2: scan
// grid 64 = (dir<<5)|b, block 1024.
// Thread (kg=tid>>8, j=tid&255) accumulates partial dots over k in
// [kg*64, kg*64+64) for the 3 gate columns {j, j+256, j+512}.
// LDS partial reduce, then threads 0..255 do the gate math + h update.
__global__ __launch_bounds__(1024) void gru_scan_kernel(
    const float* __restrict__ xp,      // [2][T][B][H3]
    const float* __restrict__ rk_f,    // [H][H3]
    const float* __restrict__ rk_b,
    const float* __restrict__ bias_f,  // [2][H3]
    const float* __restrict__ bias_b,
    float* __restrict__ hcat)          // [T][B][2H]
{
    const int bid = blockIdx.x;
    const int dir = bid >> 5;
    const int b   = bid & 31;
    const int tid = threadIdx.x;
    const int kg  = tid >> 8;          // 0..3
    const int j   = tid & 255;
    const int k0  = kg << 6;           // kg*64
    const float* rk   = dir ? rk_b : rk_f;
    const float* bias = dir ? bias_b : bias_f;
    const float rbz = bias[H3 + j];
    const float rbr = bias[H3 + 256 + j];
    const float rbh = bias[H3 + 512 + j];

    __shared__ float h[256];
    __shared__ float part[3][4][256];  // [gate][kg][j], 12 KB
    if (tid < 256) h[tid] = 0.f;
    __syncthreads();

    for (int s = 0; s < T; ++s) {
        const float* xrow = xp + ((dir * T + s) * B + b) * H3;

        float az = 0.f, ar = 0.f, ah = 0.f;
#pragma unroll 4
        for (int k = k0; k < k0 + 64; k += 4) {
            float4 h4 = *(const float4*)&h[k];              // LDS broadcast
            const float* rkp = rk + k * H3 + j;
            az += h4.x * rkp[0];
            ar += h4.x * rkp[256];
            ah += h4.x * rkp[512];
            az += h4.y * rkp[H3];
            ar += h4.y * rkp[H3 + 256];
            ah += h4.y * rkp[H3 + 512];
            az += h4.z * rkp[2 * H3];
            ar += h4.z * rkp[2 * H3 + 256];
            ah += h4.z * rkp[2 * H3 + 512];
            az += h4.w * rkp[3 * H3];
            ar += h4.w * rkp[3 * H3 + 256];
            ah += h4.w * rkp[3 * H3 + 512];
        }
        part[0][kg][j] = az;
        part[1][kg][j] = ar;
        part[2][kg][j] = ah;
        __syncthreads();                                    // partials visible

        if (tid < 256) {
            const float sz = part[0][0][tid] + part[0][1][tid]
                           + part[0][2][tid] + part[0][3][tid];
            const float sr = part[1][0][tid] + part[1][1][tid]
                           + part[1][2][tid] + part[1][3][tid];
            const float sh = part[2][0][tid] + part[2][1][tid]
                           + part[2][2][tid] + part[2][3][tid];
            const float xz = xrow[tid];
            const float xr = xrow[256 + tid];
            const float xh = xrow[512 + tid];
            const float z  = 1.f / (1.f + __expf(-(xz + sz + rbz)));
            const float r  = 1.f / (1.f + __expf(-(xr + sr + rbr)));
            const float pre = xh + r * (sh + rbh);
            const float e2  = __expf(2.f * pre);
            const float hh  = 1.f - 2.f / (e2 + 1.f);       // tanh, inf-safe
            const float hn  = z * h[tid] + (1.f - z) * hh;
            h[tid] = hn;                                    // only tid<256 touch h here
            const int ta = dir ? (T - 1 - s) : s;           // actual time
            hcat[(ta * B + b) * (2 * H) + dir * H + tid] = hn;
        }
        __syncthreads();                                    // new h visible
    }
}

// ---------------------------------------------------------------- K3: classifier
// grid 2080 (1-D, ct-major so consecutive blocks share the same W slice ->
// per-XCD L2 holds ~1-3 MB of W instead of all 13.6 MB).
// Block = 32 rows x 512 cols; thread = 2 cols x 32 rows.
__global__ __launch_bounds__(256) void cls_kernel(
    const float* __restrict__ hcat,    // [5120][512]
    const float* __restrict__ W,       // [512][C]
    const float* __restrict__ bias,    // [C]
    float* __restrict__ out)           // [5120][C]
{
    const int bid = blockIdx.x;
    const int ct  = bid / 160;         // 0..12   (same ct adjacent in bid)
    const int rt  = bid % 160;         // 0..159
    const int tid = threadIdx.x;
    const int r0  = rt * 32;

    __shared__ float hs[32 * 512];     // 64 KB
    for (int it = 0; it < 16; ++it) {
        int v   = it * 256 + tid;
        int row = v >> 7;
        int k4  = v & 127;
        *(float4*)&hs[(row << 9) + (k4 << 2)] =
            *(const float4*)&hcat[((r0 + row) << 9) + (k4 << 2)];
    }
    __syncthreads();

    const int c0 = ct * 512 + tid;     // always < 6625 (max 6399)
    const int c1 = c0 + 256;
    const bool v1 = (c1 < C);

    float acc0[32], acc1[32];
#pragma unroll
    for (int r = 0; r < 32; ++r) { acc0[r] = 0.f; acc1[r] = 0.f; }

    for (int k = 0; k < 512; k += 4) {
        const float* wp = W + k * C;
        float w00 = wp[c0];
        float w01 = wp[C + c0];
        float w02 = wp[2 * C + c0];
        float w03 = wp[3 * C + c0];
        float w10 = v1 ? wp[c1] : 0.f;
        float w11 = v1 ? wp[C + c1] : 0.f;
        float w12 = v1 ? wp[2 * C + c1] : 0.f;
        float w13 = v1 ? wp[3 * C + c1] : 0.f;
#pragma unroll
        for (int r = 0; r < 32; ++r) {
            float4 hv = *(const float4*)&hs[(r << 9) + k];  // broadcast read
            acc0[r] += hv.x * w00 + hv.y * w01 + hv.z * w02 + hv.w * w03;
            acc1[r] += hv.x * w10 + hv.y * w11 + hv.z * w12 + hv.w * w13;
        }
    }

    const float b0 = bias[c0];
    const float b1 = v1 ? bias[c1] : 0.f;
    for (int r = 0; r < 32; ++r) {
        out[(size_t)(r0 + r) * C + c0] = acc0[r] + b0;
        if (v1) out[(size_t)(r0 + r) * C + c1] = acc1[r] + b1;
    }
}

// ---------------------------------------------------------------- launch
extern "C" void kernel_launch(void* const* d_in, const int* in_sizes, int n_in,
                              void* d_out, int out_size, void* d_ws, size_t ws_size,
                              hipStream_t stream) {
    const float* x       = (const float*)d_in[0];
    const float* kf      = (const float*)d_in[1];
    const float* rkf     = (const float*)d_in[2];
    const float* biasf   = (const float*)d_in[3];
    const float* kb      = (const float*)d_in[4];
    const float* rkb     = (const float*)d_in[5];
    const float* biasb   = (const float*)d_in[6];
    const float* W       = (const float*)d_in[7];
    const float* bvec    = (const float*)d_in[8];
    float* out = (float*)d_out;

    const size_t xp_elems   = (size_t)2 * T * B * H3;   // 7,864,320
    const size_t hcat_elems = (size_t)T * B * 2 * H;    // 2,621,440

    float* xp;
    float* hcat;
    if (ws_size >= (xp_elems + hcat_elems) * sizeof(float)) {
        xp   = (float*)d_ws;
        hcat = xp + xp_elems;
    } else {
        // xp is dead before K3 writes out: reuse d_out as xp scratch.
        xp   = out;                 // 7.86M floats <= out_size 33.92M
        hcat = (float*)d_ws;        // needs 10.5 MB
    }

    dim3 g1(3, T, 2);
    proj_kernel<<<g1, 256, 0, stream>>>(x, kf, kb, biasf, biasb, xp);

    gru_scan_kernel<<<64, 1024, 0, stream>>>(xp, rkf, rkb, biasf, biasb, hcat);

    cls_kernel<<<13 * 160, 256, 0, stream>>>(hcat, W, bvec, out);
}

// Round 3
// 1023.347 us; speedup vs baseline: 2.1962x; 1.9438x over previous
//
#include <hip/hip_runtime.h>
#include <hip/hip_bf16.h>

// Bidirectional GRU (Keras reset_after=True) + dense classifier.
// B=32, T=160, D=512, H=256, C=6625.
// Round 3: scan weights -> packed bf16x2 (halve per-CU L2 bytes; scan was
//          per-CU-L2-BW-bound at ~50 B/cyc). Classifier -> bf16 MFMA with
//          pre-packed W fragments. proj unchanged fp32.

#define B 32
#define T 160
#define D 512
#define H 256
#define C 6625
#define H3 768
#define NT16 416                  // padded 16-col W tiles (415 real + 1 zero)
#define RKP_PER_DIR (128 * H3)    // 98304 dwords per direction

typedef __attribute__((ext_vector_type(8))) short short8v;
typedef __attribute__((ext_vector_type(4))) float float4v;

__device__ inline unsigned short f2bf(float v) {
    __hip_bfloat16 b = __float2bfloat16(v);
    return *reinterpret_cast<unsigned short*>(&b);
}
__device__ inline float bflo(unsigned int u) { return __uint_as_float(u << 16); }
__device__ inline float bfhi(unsigned int u) { return __uint_as_float(u & 0xffff0000u); }

// ---------------------------------------------------------------- pack rk
// rkP[dir][p][c] = bf16x2( rk[2p][c], rk[2p+1][c] ), p=0..127, c=0..767
__global__ __launch_bounds__(256) void pack_rk_kernel(
    const float* __restrict__ rkf, const float* __restrict__ rkb,
    unsigned int* __restrict__ rkP)
{
    const int idx = blockIdx.x * 256 + threadIdx.x;   // 0..98303
    const int dir = blockIdx.y;
    const float* rk = dir ? rkb : rkf;
    const int p = idx / H3;
    const int c = idx - p * H3;
    unsigned int lo = f2bf(rk[(2 * p) * H3 + c]);
    unsigned int hi = f2bf(rk[(2 * p + 1) * H3 + c]);
    rkP[dir * RKP_PER_DIR + idx] = (hi << 16) | lo;
}

// ---------------------------------------------------------------- pack W
// Wp[nt][kc][col][i] = bf16( W[kc*8+i][nt*16+col] ), zero-padded cols.
// Lane fragment load becomes one contiguous 16B read.
__global__ __launch_bounds__(256) void pack_W_kernel(
    const float* __restrict__ W, unsigned short* __restrict__ Wp)
{
    const int idx = blockIdx.x * 256 + threadIdx.x;   // < 416*8192
    const int i   = idx & 7;
    const int col = (idx >> 3) & 15;
    const int kc  = (idx >> 7) & 63;
    const int nt  = idx >> 13;
    const int k = kc * 8 + i;
    const int c = nt * 16 + col;
    const float v = (c < C) ? W[k * C + c] : 0.f;
    Wp[idx] = f2bf(v);
}

// ---------------------------------------------------------------- K1: proj
__global__ __launch_bounds__(256) void proj_kernel(
    const float* __restrict__ x,       // [B][T][D]
    const float* __restrict__ kf,      // [D][H3]
    const float* __restrict__ kb,
    const float* __restrict__ bias_f,  // [2][H3]
    const float* __restrict__ bias_b,
    float* __restrict__ xp)            // [2][T][B][H3]
{
    const int ct  = blockIdx.x;
    const int s   = blockIdx.y;
    const int dir = blockIdx.z;
    const int tid = threadIdx.x;
    const int t   = dir ? (T - 1 - s) : s;
    const float* kern = dir ? kb : kf;
    const float* bias = dir ? bias_b : bias_f;

    __shared__ float xs[32 * 512];
    for (int it = 0; it < 16; ++it) {
        int v   = it * 256 + tid;
        int row = v >> 7;
        int k4  = v & 127;
        *(float4*)&xs[(row << 9) + (k4 << 2)] =
            *(const float4*)&x[((row * T + t) << 9) + (k4 << 2)];
    }
    __syncthreads();

    const int col = ct * 256 + tid;
    float acc[32];
#pragma unroll
    for (int r = 0; r < 32; ++r) acc[r] = 0.f;

    for (int k = 0; k < 512; k += 4) {
        float w0 = kern[(k + 0) * H3 + col];
        float w1 = kern[(k + 1) * H3 + col];
        float w2 = kern[(k + 2) * H3 + col];
        float w3 = kern[(k + 3) * H3 + col];
#pragma unroll
        for (int r = 0; r < 32; ++r) {
            float4 xv = *(const float4*)&xs[(r << 9) + k];
            acc[r] += xv.x * w0 + xv.y * w1 + xv.z * w2 + xv.w * w3;
        }
    }

    const float bb = bias[col];
    for (int r = 0; r < 32; ++r)
        xp[((dir * T + s) * B + r) * H3 + col] = acc[r] + bb;
}

// ---------------------------------------------------------------- K2: scan (bf16 weights)
// grid 64 = (dir<<5)|b, block 1024; thread (kg,j) does k-range [kg*64,+64)
// for gate cols {j, j+256, j+512}. Packed dword = weights for (k, k+1).
__global__ __launch_bounds__(1024) void gru_scan_bf16(
    const float* __restrict__ xp,       // [2][T][B][H3] fp32
    const unsigned int* __restrict__ rkP,
    const float* __restrict__ bias_f,
    const float* __restrict__ bias_b,
    __hip_bfloat16* __restrict__ hcatb) // [T][B][2H] bf16
{
    const int bid = blockIdx.x;
    const int dir = bid >> 5;
    const int b   = bid & 31;
    const int tid = threadIdx.x;
    const int kg  = tid >> 8;
    const int j   = tid & 255;
    const int k0  = kg << 6;
    const unsigned int* rk = rkP + dir * RKP_PER_DIR;
    const float* bias = dir ? bias_b : bias_f;
    const float rbz = bias[H3 + j];
    const float rbr = bias[H3 + 256 + j];
    const float rbh = bias[H3 + 512 + j];

    __shared__ float h[256];
    __shared__ float part[3][4][256];
    if (tid < 256) h[tid] = 0.f;
    __syncthreads();

    for (int s = 0; s < T; ++s) {
        const float* xrow = xp + ((dir * T + s) * B + b) * H3;

        float az = 0.f, ar = 0.f, ah = 0.f;
#pragma unroll 4
        for (int k = k0; k < k0 + 64; k += 4) {
            float4 h4 = *(const float4*)&h[k];
            const unsigned int* rp = rk + (k >> 1) * H3 + j;
            unsigned int uz0 = rp[0];
            unsigned int ur0 = rp[256];
            unsigned int uh0 = rp[512];
            unsigned int uz1 = rp[H3];
            unsigned int ur1 = rp[H3 + 256];
            unsigned int uh1 = rp[H3 + 512];
            az += h4.x * bflo(uz0) + h4.y * bfhi(uz0)
                + h4.z * bflo(uz1) + h4.w * bfhi(uz1);
            ar += h4.x * bflo(ur0) + h4.y * bfhi(ur0)
                + h4.z * bflo(ur1) + h4.w * bfhi(ur1);
            ah += h4.x * bflo(uh0) + h4.y * bfhi(uh0)
                + h4.z * bflo(uh1) + h4.w * bfhi(uh1);
        }
        part[0][kg][j] = az;
        part[1][kg][j] = ar;
        part[2][kg][j] = ah;
        __syncthreads();

        if (tid < 256) {
            const float sz = part[0][0][tid] + part[0][1][tid]
                           + part[0][2][tid] + part[0][3][tid];
            const float sr = part[1][0][tid] + part[1][1][tid]
                           + part[1][2][tid] + part[1][3][tid];
            const float sh = part[2][0][tid] + part[2][1][tid]
                           + part[2][2][tid] + part[2][3][tid];
            const float xz = xrow[tid];
            const float xr = xrow[256 + tid];
            const float xh = xrow[512 + tid];
            const float z  = 1.f / (1.f + __expf(-(xz + sz + rbz)));
            const float r  = 1.f / (1.f + __expf(-(xr + sr + rbr)));
            const float pre = xh + r * (sh + rbh);
            const float e2  = __expf(2.f * pre);
            const float hh  = 1.f - 2.f / (e2 + 1.f);
            const float hn  = z * h[tid] + (1.f - z) * hh;
            h[tid] = hn;
            const int ta = dir ? (T - 1 - s) : s;
            hcatb[(ta * B + b) * (2 * H) + dir * H + tid] = __float2bfloat16(hn);
        }
        __syncthreads();
    }
}

// ---------------------------------------------------------------- K3: MFMA classifier
// grid (80,104), block 256 = 4 waves (2x2). Wave tile 32x32, block 64x64.
// A = hcatb [5120][512] bf16 (direct global), B = Wp packed fragments.
__global__ __launch_bounds__(256) void cls_mfma_kernel(
    const __hip_bfloat16* __restrict__ hcatb,
    const unsigned short* __restrict__ Wp,
    const float* __restrict__ bias,
    float* __restrict__ out)
{
    const int lane = threadIdx.x & 63;
    const int wid  = threadIdx.x >> 6;
    const int wm = wid >> 1, wn = wid & 1;
    const int rowBase = blockIdx.x * 64 + wm * 32;
    const int colBase = blockIdx.y * 64 + wn * 32;
    const int lrow = lane & 15;
    const int lk8  = lane >> 4;        // 0..3

    float4v acc[2][2] = {{{0.f,0.f,0.f,0.f},{0.f,0.f,0.f,0.f}},
                         {{0.f,0.f,0.f,0.f},{0.f,0.f,0.f,0.f}}};
    const short* A  = (const short*)hcatb;
    const short* Bp = (const short*)Wp;

    for (int k0 = 0; k0 < 512; k0 += 32) {
        short8v aF[2], bF[2];
#pragma unroll
        for (int mt = 0; mt < 2; ++mt)
            aF[mt] = *(const short8v*)&A[(rowBase + mt * 16 + lrow) * 512 + k0 + lk8 * 8];
#pragma unroll
        for (int ntw = 0; ntw < 2; ++ntw) {
            const int nt16 = blockIdx.y * 4 + wn * 2 + ntw;
            bF[ntw] = *(const short8v*)&Bp[(nt16 * 64 + (k0 >> 3) + lk8) * 128 + lrow * 8];
        }
#pragma unroll
        for (int mt = 0; mt < 2; ++mt)
#pragma unroll
            for (int ntw = 0; ntw < 2; ++ntw)
                acc[mt][ntw] = __builtin_amdgcn_mfma_f32_16x16x32_bf16(
                    aF[mt], bF[ntw], acc[mt][ntw], 0, 0, 0);
    }

    const int orow = (lane >> 4) * 4;   // C/D: col=lane&15, row=(lane>>4)*4+reg
#pragma unroll
    for (int ntw = 0; ntw < 2; ++ntw) {
        const int c = colBase + ntw * 16 + lrow;
        if (c >= C) continue;
        const float bc = bias[c];
#pragma unroll
        for (int mt = 0; mt < 2; ++mt)
#pragma unroll
            for (int v = 0; v < 4; ++v)
                out[(size_t)(rowBase + mt * 16 + orow + v) * C + c] = acc[mt][ntw][v] + bc;
    }
}

// ============================ fallback fp32 path (small ws) ============================
__global__ __launch_bounds__(1024) void gru_scan_f32(
    const float* __restrict__ xp,
    const float* __restrict__ rk_f, const float* __restrict__ rk_b,
    const float* __restrict__ bias_f, const float* __restrict__ bias_b,
    float* __restrict__ hcat)
{
    const int bid = blockIdx.x;
    const int dir = bid >> 5;
    const int b   = bid & 31;
    const int tid = threadIdx.x;
    const int kg  = tid >> 8;
    const int j   = tid & 255;
    const int k0  = kg << 6;
    const float* rk   = dir ? rk_b : rk_f;
    const float* bias = dir ? bias_b : bias_f;
    const float rbz = bias[H3 + j];
    const float rbr = bias[H3 + 256 + j];
    const float rbh = bias[H3 + 512 + j];

    __shared__ float h[256];
    __shared__ float part[3][4][256];
    if (tid < 256) h[tid] = 0.f;
    __syncthreads();

    for (int s = 0; s < T; ++s) {
        const float* xrow = xp + ((dir * T + s) * B + b) * H3;
        float az = 0.f, ar = 0.f, ah = 0.f;
#pragma unroll 4
        for (int k = k0; k < k0 + 64; k += 4) {
            float4 h4 = *(const float4*)&h[k];
            const float* rkp = rk + k * H3 + j;
            az += h4.x * rkp[0];       ar += h4.x * rkp[256];       ah += h4.x * rkp[512];
            az += h4.y * rkp[H3];      ar += h4.y * rkp[H3+256];    ah += h4.y * rkp[H3+512];
            az += h4.z * rkp[2*H3];    ar += h4.z * rkp[2*H3+256];  ah += h4.z * rkp[2*H3+512];
            az += h4.w * rkp[3*H3];    ar += h4.w * rkp[3*H3+256];  ah += h4.w * rkp[3*H3+512];
        }
        part[0][kg][j] = az; part[1][kg][j] = ar; part[2][kg][j] = ah;
        __syncthreads();
        if (tid < 256) {
            const float sz = part[0][0][tid]+part[0][1][tid]+part[0][2][tid]+part[0][3][tid];
            const float sr = part[1][0][tid]+part[1][1][tid]+part[1][2][tid]+part[1][3][tid];
            const float sh = part[2][0][tid]+part[2][1][tid]+part[2][2][tid]+part[2][3][tid];
            const float xz = xrow[tid], xr = xrow[256+tid], xh = xrow[512+tid];
            const float z  = 1.f / (1.f + __expf(-(xz + sz + rbz)));
            const float r  = 1.f / (1.f + __expf(-(xr + sr + rbr)));
            const float pre = xh + r * (sh + rbh);
            const float e2  = __expf(2.f * pre);
            const float hh  = 1.f - 2.f / (e2 + 1.f);
            const float hn  = z * h[tid] + (1.f - z) * hh;
            h[tid] = hn;
            const int ta = dir ? (T - 1 - s) : s;
            hcat[(ta * B + b) * (2 * H) + dir * H + tid] = hn;
        }
        __syncthreads();
    }
}

__global__ __launch_bounds__(256) void cls_f32_kernel(
    const float* __restrict__ hcat, const float* __restrict__ W,
    const float* __restrict__ bias, float* __restrict__ out)
{
    const int bid = blockIdx.x;
    const int ct  = bid / 160;
    const int rt  = bid % 160;
    const int tid = threadIdx.x;
    const int r0  = rt * 32;

    __shared__ float hs[32 * 512];
    for (int it = 0; it < 16; ++it) {
        int v = it * 256 + tid, row = v >> 7, k4 = v & 127;
        *(float4*)&hs[(row << 9) + (k4 << 2)] =
            *(const float4*)&hcat[((r0 + row) << 9) + (k4 << 2)];
    }
    __syncthreads();

    const int c0 = ct * 512 + tid;
    const int c1 = c0 + 256;
    const bool v1 = (c1 < C);
    float acc0[32], acc1[32];
#pragma unroll
    for (int r = 0; r < 32; ++r) { acc0[r] = 0.f; acc1[r] = 0.f; }
    for (int k = 0; k < 512; k += 4) {
        const float* wp = W + k * C;
        float w00 = wp[c0], w01 = wp[C+c0], w02 = wp[2*C+c0], w03 = wp[3*C+c0];
        float w10 = v1 ? wp[c1] : 0.f, w11 = v1 ? wp[C+c1] : 0.f;
        float w12 = v1 ? wp[2*C+c1] : 0.f, w13 = v1 ? wp[3*C+c1] : 0.f;
#pragma unroll
        for (int r = 0; r < 32; ++r) {
            float4 hv = *(const float4*)&hs[(r << 9) + k];
            acc0[r] += hv.x*w00 + hv.y*w01 + hv.z*w02 + hv.w*w03;
            acc1[r] += hv.x*w10 + hv.y*w11 + hv.z*w12 + hv.w*w13;
        }
    }
    const float b0 = bias[c0];
    const float b1 = v1 ? bias[c1] : 0.f;
    for (int r = 0; r < 32; ++r) {
        out[(size_t)(r0+r)*C + c0] = acc0[r] + b0;
        if (v1) out[(size_t)(r0+r)*C + c1] = acc1[r] + b1;
    }
}

// ---------------------------------------------------------------- launch
extern "C" void kernel_launch(void* const* d_in, const int* in_sizes, int n_in,
                              void* d_out, int out_size, void* d_ws, size_t ws_size,
                              hipStream_t stream) {
    const float* x     = (const float*)d_in[0];
    const float* kf    = (const float*)d_in[1];
    const float* rkf   = (const float*)d_in[2];
    const float* biasf = (const float*)d_in[3];
    const float* kb    = (const float*)d_in[4];
    const float* rkb   = (const float*)d_in[5];
    const float* biasb = (const float*)d_in[6];
    const float* W     = (const float*)d_in[7];
    const float* bvec  = (const float*)d_in[8];
    float* out = (float*)d_out;

    const size_t rkP_bytes   = (size_t)2 * RKP_PER_DIR * 4;        //   786,432
    const size_t Wp_bytes    = (size_t)NT16 * 8192 * 2;            // 6,815,744
    const size_t hcatb_bytes = (size_t)T * B * 2 * H * 2;          // 5,242,880
    const size_t planA_bytes = rkP_bytes + Wp_bytes + hcatb_bytes; // 12,845,056

    float* xp = out;   // xp [2][T][B][H3] lives in d_out; dead before cls writes

    if (ws_size >= planA_bytes) {
        char* wsb = (char*)d_ws;
        unsigned int*   rkP   = (unsigned int*)wsb;
        unsigned short* Wp    = (unsigned short*)(wsb + rkP_bytes);
        __hip_bfloat16* hcatb = (__hip_bfloat16*)(wsb + rkP_bytes + Wp_bytes);

        pack_rk_kernel<<<dim3(384, 2), 256, 0, stream>>>(rkf, rkb, rkP);
        pack_W_kernel<<<13312, 256, 0, stream>>>(W, Wp);

        dim3 g1(3, T, 2);
        proj_kernel<<<g1, 256, 0, stream>>>(x, kf, kb, biasf, biasb, xp);

        gru_scan_bf16<<<64, 1024, 0, stream>>>(xp, rkP, biasf, biasb, hcatb);

        dim3 g3(80, 104);
        cls_mfma_kernel<<<g3, 256, 0, stream>>>(hcatb, Wp, bvec, out);
    } else {
        // fp32 fallback (round-2 path)
        float* hcat = (float*)d_ws;     // 10.5 MB
        dim3 g1(3, T, 2);
        proj_kernel<<<g1, 256, 0, stream>>>(x, kf, kb, biasf, biasb, xp);
        gru_scan_f32<<<64, 1024, 0, stream>>>(xp, rkf, rkb, biasf, biasb, hcat);
        cls_f32_kernel<<<13 * 160, 256, 0, stream>>>(hcat, W, bvec, out);
    }
}